// Round 1
// baseline (217.446 us; speedup 1.0000x reference)
//
#include <hip/hip_runtime.h>
#include <hip/hip_bf16.h>
#include <math.h>

typedef __bf16 bf16x8 __attribute__((ext_vector_type(8)));
typedef float  f32x4  __attribute__((ext_vector_type(4)));
typedef float  f32x4v __attribute__((ext_vector_type(4)));
typedef unsigned short ushort_t;
typedef ushort_t u16x4 __attribute__((ext_vector_type(4)));
typedef ushort_t u16x8 __attribute__((ext_vector_type(8)));

__device__ __forceinline__ ushort_t f2bf(float f) {
    unsigned u = __builtin_bit_cast(unsigned, f);
    u += 0x7FFFu + ((u >> 16) & 1u);
    return (ushort_t)(u >> 16);
}

// ---------------- fp32 -> bf16 conversion ----------------
__global__ __launch_bounds__(256) void cvt_kernel(const float* __restrict__ in,
                                                  ushort_t* __restrict__ out, int n4) {
    int i = blockIdx.x * 256 + threadIdx.x;
    if (i >= n4) return;
    f32x4v v = ((const f32x4v*)in)[i];
    u16x4 o = { f2bf(v.x), f2bf(v.y), f2bf(v.z), f2bf(v.w) };
    ((u16x4*)out)[i] = o;
}

// ---------------- NT GEMM: C = A(MxK) * B(NxK)^T ----------------
// modes
#define M_PROJ 0   // bf16 out + bias
#define M_VPT  1   // bf16 out + bias, transposed batched store (for vp^T)
#define M_S    2   // fp32 out * scale, batched
#define M_PV   3   // bf16 out, batched
#define M_OUT  4   // fp32 out + bias

#define BM 128
#define BN 128
#define BK 32

template<int MODE>
__global__ __launch_bounds__(256, 3)
void gemm_nt(const ushort_t* __restrict__ A, int lda, long long aBatch,
             const ushort_t* __restrict__ B, int ldb, long long bBatch,
             void* __restrict__ Cv, int ldc, long long cBatch,
             const float* __restrict__ bias, float scale, int K)
{
    __shared__ __align__(16) ushort_t lds[2][2][BM * BK];
    const int tid  = threadIdx.x;
    const int lane = tid & 63;
    const int wave = tid >> 6;
    const int wr = wave >> 1, wc = wave & 1;
    const long long tM = (long long)blockIdx.y * BM;
    const long long tN = (long long)blockIdx.x * BN;
    const int z = blockIdx.z;
    const ushort_t* Ab = A + (long long)z * aBatch;
    const ushort_t* Bb = B + (long long)z * bBatch;

    f32x4 acc[4][4];
#pragma unroll
    for (int i = 0; i < 4; ++i)
#pragma unroll
        for (int j = 0; j < 4; ++j)
            acc[i][j] = (f32x4){0.f, 0.f, 0.f, 0.f};

    auto stage = [&](int buf, int kt) {
        const int k0 = kt * BK;
#pragma unroll
        for (int rnd = 0; rnd < 2; ++rnd) {
            const int c    = tid + rnd * 256;
            const int row  = c >> 2;
            const int slot = (c & 3) ^ (row & 3);     // 16B-granular XOR swizzle (source side)
            const ushort_t* ga = Ab + (tM + row) * (long long)lda + k0 + slot * 8;
            const ushort_t* gb = Bb + (tN + row) * (long long)ldb + k0 + slot * 8;
            ushort_t* la = &lds[buf][0][(rnd * 256 + wave * 64) * 8];
            ushort_t* lb = &lds[buf][1][(rnd * 256 + wave * 64) * 8];
            __builtin_amdgcn_global_load_lds((const __attribute__((address_space(1))) void*)ga,
                                             (__attribute__((address_space(3))) void*)la, 16, 0, 0);
            __builtin_amdgcn_global_load_lds((const __attribute__((address_space(1))) void*)gb,
                                             (__attribute__((address_space(3))) void*)lb, 16, 0, 0);
        }
    };

    auto compute = [&](int buf) {
        const int kb  = lane >> 4;    // which 16B slot along K
        const int r16 = lane & 15;
        bf16x8 af[4], bfr[4];
#pragma unroll
        for (int mi = 0; mi < 4; ++mi) {
            const int row = wr * 64 + mi * 16 + r16;
            const int off = row * 64 + ((kb ^ (row & 3)) << 4);   // swizzled read
            af[mi] = *(const bf16x8*)((const char*)lds[buf][0] + off);
        }
#pragma unroll
        for (int ni = 0; ni < 4; ++ni) {
            const int row = wc * 64 + ni * 16 + r16;
            const int off = row * 64 + ((kb ^ (row & 3)) << 4);
            bfr[ni] = *(const bf16x8*)((const char*)lds[buf][1] + off);
        }
#pragma unroll
        for (int mi = 0; mi < 4; ++mi)
#pragma unroll
            for (int ni = 0; ni < 4; ++ni)
                acc[mi][ni] = __builtin_amdgcn_mfma_f32_16x16x32_bf16(af[mi], bfr[ni], acc[mi][ni], 0, 0, 0);
    };

    const int NT = K / BK;
    stage(0, 0);
    __syncthreads();
    int cur = 0;
    for (int kt = 0; kt + 1 < NT; ++kt) {
        stage(cur ^ 1, kt + 1);   // prefetch next tile (async, drains at barrier)
        compute(cur);
        __syncthreads();
        cur ^= 1;
    }
    compute(cur);

    // ---------------- epilogue ----------------
    const int rquad = (lane >> 4) * 4;
    const int cl    = lane & 15;
#pragma unroll
    for (int mi = 0; mi < 4; ++mi) {
#pragma unroll
        for (int ni = 0; ni < 4; ++ni) {
            f32x4 v = acc[mi][ni];
            const long long r = tM + wr * 64 + mi * 16 + rquad;   // rows r..r+3
            const long long c = tN + wc * 64 + ni * 16 + cl;
            if constexpr (MODE == M_PROJ) {
                const float bc = bias[c];
                ushort_t* out = (ushort_t*)Cv;
#pragma unroll
                for (int j = 0; j < 4; ++j)
                    out[(r + j) * ldc + c] = f2bf(v[j] + bc);
            } else if constexpr (MODE == M_VPT) {
                const float bc = bias[c];
                ushort_t* out = (ushort_t*)Cv;
                const long long b  = r >> 11;
                const long long i0 = r & 2047;
                u16x4 pk = { f2bf(v[0] + bc), f2bf(v[1] + bc), f2bf(v[2] + bc), f2bf(v[3] + bc) };
                *(u16x4*)(out + (b * 768 + c) * 2048 + i0) = pk;
            } else if constexpr (MODE == M_S) {
                float* out = (float*)Cv + (long long)z * cBatch;
#pragma unroll
                for (int j = 0; j < 4; ++j)
                    out[(r + j) * ldc + c] = v[j] * scale;
            } else if constexpr (MODE == M_PV) {
                ushort_t* out = (ushort_t*)Cv + (long long)z * cBatch;
#pragma unroll
                for (int j = 0; j < 4; ++j)
                    out[(r + j) * ldc + c] = f2bf(v[j]);
            } else {  // M_OUT
                const float bc = bias[c];
                float* out = (float*)Cv;
#pragma unroll
                for (int j = 0; j < 4; ++j)
                    out[(r + j) * ldc + c] = v[j] + bc;
            }
        }
    }
}

// ---------------- row softmax, fp32 in, bf16 out in place ----------------
__global__ __launch_bounds__(256) void softmax_kernel(float* __restrict__ S) {
    const long long row = blockIdx.x;
    float* srow = S + row * 2048;
    const int tid = threadIdx.x;
    const int lane = tid & 63, wave = tid >> 6;

    f32x4v v0 = ((const f32x4v*)srow)[tid * 2];
    f32x4v v1 = ((const f32x4v*)srow)[tid * 2 + 1];
    float vals[8] = { v0.x, v0.y, v0.z, v0.w, v1.x, v1.y, v1.z, v1.w };

    float m = vals[0];
#pragma unroll
    for (int i = 1; i < 8; ++i) m = fmaxf(m, vals[i]);
#pragma unroll
    for (int off = 32; off; off >>= 1) m = fmaxf(m, __shfl_xor(m, off, 64));
    __shared__ float redm[4];
    if (lane == 0) redm[wave] = m;
    __syncthreads();
    m = fmaxf(fmaxf(redm[0], redm[1]), fmaxf(redm[2], redm[3]));

    float e[8];
    float s = 0.f;
#pragma unroll
    for (int i = 0; i < 8; ++i) { e[i] = __expf(vals[i] - m); s += e[i]; }
#pragma unroll
    for (int off = 32; off; off >>= 1) s += __shfl_xor(s, off, 64);
    __shared__ float reds[4];
    if (lane == 0) reds[wave] = s;
    __syncthreads();
    s = reds[0] + reds[1] + reds[2] + reds[3];
    const float inv = 1.0f / s;

    u16x8 o = { f2bf(e[0] * inv), f2bf(e[1] * inv), f2bf(e[2] * inv), f2bf(e[3] * inv),
                f2bf(e[4] * inv), f2bf(e[5] * inv), f2bf(e[6] * inv), f2bf(e[7] * inv) };
    ((u16x8*)srow)[tid] = o;   // bf16 P overwrites first half of the fp32 row (safe: all reads done)
}

// ---------------- launch ----------------
extern "C" void kernel_launch(void* const* d_in, const int* in_sizes, int n_in,
                              void* d_out, int out_size, void* d_ws, size_t ws_size,
                              hipStream_t stream) {
    (void)in_sizes; (void)n_in; (void)out_size; (void)ws_size;
    const float* q  = (const float*)d_in[0];
    const float* k  = (const float*)d_in[1];
    const float* v  = (const float*)d_in[2];
    const float* Wq = (const float*)d_in[3];
    const float* bq = (const float*)d_in[4];
    const float* Wk = (const float*)d_in[5];
    const float* bk = (const float*)d_in[6];
    const float* Wv = (const float*)d_in[7];
    const float* bv = (const float*)d_in[8];
    const float* Wp = (const float*)d_in[9];
    const float* bp = (const float*)d_in[10];
    float* out = (float*)d_out;

    char* ws = (char*)d_ws;
    // region 0: bf16 copies of q,k,v -> later overlaid by S (67.1 MB)
    ushort_t* qb  = (ushort_t*)(ws);
    ushort_t* kb  = (ushort_t*)(ws + 12582912LL);
    ushort_t* vb  = (ushort_t*)(ws + 25165824LL);
    float*    S   = (float*)(ws);                    // 4*2048*2048 fp32
    ushort_t* Wqb = (ushort_t*)(ws + 67108864LL);
    ushort_t* Wkb = (ushort_t*)(ws + 68288512LL);
    ushort_t* Wvb = (ushort_t*)(ws + 69468160LL);
    ushort_t* Wpb = (ushort_t*)(ws + 70647808LL);
    ushort_t* qp  = (ushort_t*)(ws + 71827456LL);    // [8192][768] bf16
    ushort_t* kp  = (ushort_t*)(ws + 84410368LL);    // [8192][768] bf16
    ushort_t* vpT = (ushort_t*)(ws + 96993280LL);    // [4][768][2048] bf16
    ushort_t* Ob  = qp;                              // O overlays dead qp

    const float scale = 1.0f / sqrtf(768.0f);

    cvt_kernel<<<6144, 256, 0, stream>>>(q, qb, 1572864);
    cvt_kernel<<<6144, 256, 0, stream>>>(k, kb, 1572864);
    cvt_kernel<<<6144, 256, 0, stream>>>(v, vb, 1572864);
    cvt_kernel<<<576, 256, 0, stream>>>(Wq, Wqb, 147456);
    cvt_kernel<<<576, 256, 0, stream>>>(Wk, Wkb, 147456);
    cvt_kernel<<<576, 256, 0, stream>>>(Wv, Wvb, 147456);
    cvt_kernel<<<576, 256, 0, stream>>>(Wp, Wpb, 147456);

    // projections: [8192x768] = [8192x768] @ [768x768]^T
    gemm_nt<M_PROJ><<<dim3(6, 64, 1), 256, 0, stream>>>(qb, 768, 0, Wqb, 768, 0, qp, 768, 0, bq, 1.0f, 768);
    gemm_nt<M_PROJ><<<dim3(6, 64, 1), 256, 0, stream>>>(kb, 768, 0, Wkb, 768, 0, kp, 768, 0, bk, 1.0f, 768);
    gemm_nt<M_VPT> <<<dim3(6, 64, 1), 256, 0, stream>>>(vb, 768, 0, Wvb, 768, 0, vpT, 0, 0, bv, 1.0f, 768);

    // S[b] = scale * qp[b] @ kp[b]^T   (2048x2048x768, batched over 4)
    gemm_nt<M_S><<<dim3(16, 16, 4), 256, 0, stream>>>(qp, 768, 1572864, kp, 768, 1572864,
                                                      S, 2048, 4194304, nullptr, scale, 768);
    // row softmax (S fp32 -> P bf16 in place)
    softmax_kernel<<<8192, 256, 0, stream>>>(S);

    // O[b] = P[b] @ vpT[b]^T   (2048x768x2048; P rows live at stride 4096 bf16 elems)
    gemm_nt<M_PV><<<dim3(6, 16, 4), 256, 0, stream>>>((const ushort_t*)S, 4096, 8388608,
                                                      vpT, 2048, 1572864, Ob, 768, 1572864,
                                                      nullptr, 1.0f, 2048);
    // out = O @ Wp^T + bp  (fp32 out)
    gemm_nt<M_OUT><<<dim3(6, 64, 1), 256, 0, stream>>>(Ob, 768, 0, Wpb, 768, 0, out, 768, 0, bp, 1.0f, 768);
}

// Round 2
// 171.041 us; speedup vs baseline: 1.2713x; 1.2713x over previous
//
#include <hip/hip_runtime.h>
#include <hip/hip_bf16.h>
#include <math.h>

typedef __bf16 bf16x8 __attribute__((ext_vector_type(8)));
typedef float  f32x4  __attribute__((ext_vector_type(4)));
typedef float  f32x4v __attribute__((ext_vector_type(4)));
typedef unsigned short ushort_t;
typedef ushort_t u16x4 __attribute__((ext_vector_type(4)));
typedef ushort_t u16x8 __attribute__((ext_vector_type(8)));

__device__ __forceinline__ ushort_t f2bf(float f) {
    unsigned u = __builtin_bit_cast(unsigned, f);
    u += 0x7FFFu + ((u >> 16) & 1u);
    return (ushort_t)(u >> 16);
}
__device__ __forceinline__ float bf2f(ushort_t b) {
    return __builtin_bit_cast(float, (unsigned)b << 16);
}

// XCD-aware bijective remap: hardware block lin -> work id (m157/m204 pattern).
// Requires total grid % 8 == 0 (all our grids satisfy this).
__device__ __forceinline__ void xcd_remap(int& bx, int& by, int& bz) {
    const int gx = gridDim.x, gy = gridDim.y;
    const int nwg = gx * gy * gridDim.z;
    const int lin = (blockIdx.z * gy + blockIdx.y) * gx + blockIdx.x;
    const int chunk = nwg >> 3;
    int nid = (lin & 7) * chunk + (lin >> 3);
    bx = nid % gx; nid /= gx;
    by = nid % gy; bz = nid / gy;
}

// ---------------- fp32 -> bf16 conversion (z-batched, up to 4 arrays) --------
__global__ __launch_bounds__(256) void cvt_multi(const float* __restrict__ i0, const float* __restrict__ i1,
                                                 const float* __restrict__ i2, const float* __restrict__ i3,
                                                 ushort_t* __restrict__ o0, ushort_t* __restrict__ o1,
                                                 ushort_t* __restrict__ o2, ushort_t* __restrict__ o3, int n4) {
    const int z = blockIdx.z;
    const float* in  = z == 0 ? i0 : z == 1 ? i1 : z == 2 ? i2 : i3;
    ushort_t*    out = z == 0 ? o0 : z == 1 ? o1 : z == 2 ? o2 : o3;
    int i = blockIdx.x * 256 + threadIdx.x;
    if (i >= n4) return;
    f32x4v v = ((const f32x4v*)in)[i];
    u16x4 o = { f2bf(v.x), f2bf(v.y), f2bf(v.z), f2bf(v.w) };
    ((u16x4*)out)[i] = o;
}

__global__ __launch_bounds__(256) void zero_f32(float* __restrict__ p, int n) {
    int i = blockIdx.x * 256 + threadIdx.x;
    if (i < n) p[i] = 0.f;
}

// ---------------- NT GEMM: C = A(MxK) * B(NxK)^T ----------------
#define M_SEXP 0   // P~ = exp(scale*acc) bf16 out, batched, + rowsum atomics
#define M_PVN  1   // bf16 out * (1/rowsum[row]), batched
#define M_OUT  2   // fp32 out + bias

#define BM 128
#define BN 128
#define BK 32

#define GEMM_CORE(Ab_, lda_, Bb_, ldb_, Kdim_)                                              \
    __shared__ __align__(16) ushort_t lds[2][2][BM * BK];                                   \
    const int tid  = threadIdx.x;                                                           \
    const int lane = tid & 63;                                                              \
    const int wave = tid >> 6;                                                              \
    const int wr = wave >> 1, wc = wave & 1;                                                \
    f32x4 acc[4][4];                                                                        \
    _Pragma("unroll") for (int i = 0; i < 4; ++i)                                           \
        _Pragma("unroll") for (int j = 0; j < 4; ++j)                                       \
            acc[i][j] = (f32x4){0.f, 0.f, 0.f, 0.f};                                        \
    auto stage = [&](int buf, int kt) {                                                     \
        const int k0 = kt * BK;                                                             \
        _Pragma("unroll") for (int rnd = 0; rnd < 2; ++rnd) {                               \
            const int c    = tid + rnd * 256;                                               \
            const int row  = c >> 2;                                                        \
            const int slot = (c & 3) ^ (row & 3);                                           \
            const ushort_t* ga = (Ab_) + (tM + row) * (long long)(lda_) + k0 + slot * 8;    \
            const ushort_t* gb = (Bb_) + (tN + row) * (long long)(ldb_) + k0 + slot * 8;    \
            ushort_t* la = &lds[buf][0][(rnd * 256 + wave * 64) * 8];                       \
            ushort_t* lb = &lds[buf][1][(rnd * 256 + wave * 64) * 8];                       \
            __builtin_amdgcn_global_load_lds((const __attribute__((address_space(1))) void*)ga, \
                                             (__attribute__((address_space(3))) void*)la, 16, 0, 0); \
            __builtin_amdgcn_global_load_lds((const __attribute__((address_space(1))) void*)gb, \
                                             (__attribute__((address_space(3))) void*)lb, 16, 0, 0); \
        }                                                                                   \
    };                                                                                      \
    auto compute = [&](int buf) {                                                           \
        const int kb  = lane >> 4;                                                          \
        const int r16 = lane & 15;                                                          \
        bf16x8 af[4], bfr[4];                                                               \
        _Pragma("unroll") for (int mi = 0; mi < 4; ++mi) {                                  \
            const int row = wr * 64 + mi * 16 + r16;                                        \
            const int off = row * 64 + ((kb ^ (row & 3)) << 4);                             \
            af[mi] = *(const bf16x8*)((const char*)lds[buf][0] + off);                      \
        }                                                                                   \
        _Pragma("unroll") for (int ni = 0; ni < 4; ++ni) {                                  \
            const int row = wc * 64 + ni * 16 + r16;                                        \
            const int off = row * 64 + ((kb ^ (row & 3)) << 4);                             \
            bfr[ni] = *(const bf16x8*)((const char*)lds[buf][1] + off);                     \
        }                                                                                   \
        _Pragma("unroll") for (int mi = 0; mi < 4; ++mi)                                    \
            _Pragma("unroll") for (int ni = 0; ni < 4; ++ni)                                \
                acc[mi][ni] = __builtin_amdgcn_mfma_f32_16x16x32_bf16(af[mi], bfr[ni], acc[mi][ni], 0, 0, 0); \
    };                                                                                      \
    const int NT = (Kdim_) / BK;                                                            \
    stage(0, 0);                                                                            \
    __syncthreads();                                                                        \
    int cur = 0;                                                                            \
    for (int kt = 0; kt + 1 < NT; ++kt) {                                                   \
        stage(cur ^ 1, kt + 1);                                                             \
        compute(cur);                                                                       \
        __syncthreads();                                                                    \
        cur ^= 1;                                                                           \
    }                                                                                       \
    compute(cur);                                                                           \
    const int rquad = (lane >> 4) * 4;                                                      \
    const int cl    = lane & 15;

template<int MODE>
__global__ __launch_bounds__(256, 3)
void gemm_nt(const ushort_t* __restrict__ A, int lda, long long aBatch,
             const ushort_t* __restrict__ B, int ldb, long long bBatch,
             void* __restrict__ Cv, int ldc, long long cBatch,
             const float* __restrict__ bias, float* __restrict__ rowsum,
             float scale, int K)
{
    int bx, by, bz;
    xcd_remap(bx, by, bz);
    const long long tM = (long long)by * BM;
    const long long tN = (long long)bx * BN;
    const int z = bz;
    const ushort_t* Ab = A + (long long)z * aBatch;
    const ushort_t* Bb = B + (long long)z * bBatch;

    GEMM_CORE(Ab, lda, Bb, ldb, K)

#pragma unroll
    for (int mi = 0; mi < 4; ++mi) {
        const long long r = tM + wr * 64 + mi * 16 + rquad;   // rows r..r+3
        if constexpr (MODE == M_SEXP) {
            ushort_t* out = (ushort_t*)Cv + (long long)z * cBatch;
            float rs[4] = {0.f, 0.f, 0.f, 0.f};
#pragma unroll
            for (int ni = 0; ni < 4; ++ni) {
                f32x4 v = acc[mi][ni];
                const long long c = tN + wc * 64 + ni * 16 + cl;
#pragma unroll
                for (int j = 0; j < 4; ++j) {
                    float p = __expf(v[j] * scale);
                    ushort_t pb = f2bf(p);
                    out[(r + j) * ldc + c] = pb;
                    rs[j] += bf2f(pb);     // sum exactly what PV will read
                }
            }
#pragma unroll
            for (int j = 0; j < 4; ++j) {
                float s = rs[j];
                s += __shfl_xor(s, 1, 64);
                s += __shfl_xor(s, 2, 64);
                s += __shfl_xor(s, 4, 64);
                s += __shfl_xor(s, 8, 64);
                if (cl == 0) atomicAdd(&rowsum[(long long)z * 2048 + r + j], s);
            }
        } else if constexpr (MODE == M_PVN) {
            ushort_t* out = (ushort_t*)Cv + (long long)z * cBatch;
            float inv[4];
#pragma unroll
            for (int j = 0; j < 4; ++j)
                inv[j] = 1.0f / rowsum[(long long)z * 2048 + r + j];
#pragma unroll
            for (int ni = 0; ni < 4; ++ni) {
                f32x4 v = acc[mi][ni];
                const long long c = tN + wc * 64 + ni * 16 + cl;
#pragma unroll
                for (int j = 0; j < 4; ++j)
                    out[(r + j) * ldc + c] = f2bf(v[j] * inv[j]);
            }
        } else {  // M_OUT
            float* out = (float*)Cv;
#pragma unroll
            for (int ni = 0; ni < 4; ++ni) {
                f32x4 v = acc[mi][ni];
                const long long c = tN + wc * 64 + ni * 16 + cl;
                const float bc = bias[c];
#pragma unroll
                for (int j = 0; j < 4; ++j)
                    out[(r + j) * ldc + c] = v[j] + bc;
            }
        }
    }
}

// ---------------- batched QKV projection (z picks q/k/v; z==2 stores vp^T) ---
__global__ __launch_bounds__(256, 3)
void proj_qkv(const ushort_t* __restrict__ a0, const ushort_t* __restrict__ a1, const ushort_t* __restrict__ a2,
              const ushort_t* __restrict__ w0, const ushort_t* __restrict__ w1, const ushort_t* __restrict__ w2,
              const float* __restrict__ b0, const float* __restrict__ b1, const float* __restrict__ b2,
              ushort_t* __restrict__ dq, ushort_t* __restrict__ dk, ushort_t* __restrict__ dvT)
{
    int bx, by, bz;
    xcd_remap(bx, by, bz);
    const long long tM = (long long)by * BM;
    const long long tN = (long long)bx * BN;
    const int z = bz;
    const ushort_t* Ab = z == 0 ? a0 : z == 1 ? a1 : a2;
    const ushort_t* Bb = z == 0 ? w0 : z == 1 ? w1 : w2;
    const float* bias  = z == 0 ? b0 : z == 1 ? b1 : b2;

    GEMM_CORE(Ab, 768, Bb, 768, 768)

#pragma unroll
    for (int mi = 0; mi < 4; ++mi) {
        const long long r = tM + wr * 64 + mi * 16 + rquad;
#pragma unroll
        for (int ni = 0; ni < 4; ++ni) {
            f32x4 v = acc[mi][ni];
            const long long c = tN + wc * 64 + ni * 16 + cl;
            const float bc = bias[c];
            if (z < 2) {
                ushort_t* dst = z == 0 ? dq : dk;
#pragma unroll
                for (int j = 0; j < 4; ++j)
                    dst[(r + j) * 768 + c] = f2bf(v[j] + bc);
            } else {
                // vp^T layout [4][768][2048]; r..r+3 share a batch (rquad%4==0)
                u16x4 pk = { f2bf(v[0] + bc), f2bf(v[1] + bc), f2bf(v[2] + bc), f2bf(v[3] + bc) };
                *(u16x4*)(dvT + ((r >> 11) * 768 + c) * 2048 + (r & 2047)) = pk;
            }
        }
    }
}

// ---------------- launch ----------------
extern "C" void kernel_launch(void* const* d_in, const int* in_sizes, int n_in,
                              void* d_out, int out_size, void* d_ws, size_t ws_size,
                              hipStream_t stream) {
    (void)in_sizes; (void)n_in; (void)out_size; (void)ws_size;
    const float* q  = (const float*)d_in[0];
    const float* k  = (const float*)d_in[1];
    const float* v  = (const float*)d_in[2];
    const float* Wq = (const float*)d_in[3];
    const float* bq = (const float*)d_in[4];
    const float* Wk = (const float*)d_in[5];
    const float* bk = (const float*)d_in[6];
    const float* Wv = (const float*)d_in[7];
    const float* bv = (const float*)d_in[8];
    const float* Wp = (const float*)d_in[9];
    const float* bp = (const float*)d_in[10];
    float* out = (float*)d_out;

    char* ws = (char*)d_ws;
    // phase 1: bf16 copies of q,k,v at ws+0 (dead after projections)
    ushort_t* qb  = (ushort_t*)(ws);
    ushort_t* kb  = (ushort_t*)(ws + 12582912LL);
    ushort_t* vb  = (ushort_t*)(ws + 25165824LL);
    // phase 2 overlay: P~ bf16 [4][2048][2048] + rowsum[8192]
    ushort_t* P   = (ushort_t*)(ws);
    float* rowsum = (float*)(ws + 33554432LL);
    ushort_t* Wqb = (ushort_t*)(ws + 67108864LL);
    ushort_t* Wkb = (ushort_t*)(ws + 68288512LL);
    ushort_t* Wvb = (ushort_t*)(ws + 69468160LL);
    ushort_t* Wpb = (ushort_t*)(ws + 70647808LL);
    ushort_t* qp  = (ushort_t*)(ws + 71827456LL);    // [8192][768] bf16
    ushort_t* kp  = (ushort_t*)(ws + 84410368LL);    // [8192][768] bf16
    ushort_t* vpT = (ushort_t*)(ws + 96993280LL);    // [4][768][2048] bf16
    ushort_t* Ob  = qp;                              // O overlays dead qp

    const float scale = 1.0f / sqrtf(768.0f);

    cvt_multi<<<dim3(6144, 1, 3), 256, 0, stream>>>(q, k, v, nullptr, qb, kb, vb, nullptr, 1572864);
    cvt_multi<<<dim3(576, 1, 4), 256, 0, stream>>>(Wq, Wk, Wv, Wp, Wqb, Wkb, Wvb, Wpb, 147456);

    // projections (batched): qp, kp, vpT
    proj_qkv<<<dim3(6, 64, 3), 256, 0, stream>>>(qb, kb, vb, Wqb, Wkb, Wvb, bq, bk, bv, qp, kp, vpT);

    // rowsum = 0 (vb region is dead now)
    zero_f32<<<32, 256, 0, stream>>>(rowsum, 8192);

    // P~[b] = exp(scale * qp[b] @ kp[b]^T) bf16, rowsum += partial sums
    gemm_nt<M_SEXP><<<dim3(16, 16, 4), 256, 0, stream>>>(qp, 768, 1572864, kp, 768, 1572864,
                                                         P, 2048, 4194304, nullptr, rowsum, scale, 768);

    // O[b] = (P~[b] @ vpT[b]^T) * 1/rowsum
    gemm_nt<M_PVN><<<dim3(6, 16, 4), 256, 0, stream>>>(P, 2048, 4194304, vpT, 2048, 1572864,
                                                       Ob, 768, 1572864, nullptr, rowsum, 1.0f, 2048);

    // out = O @ Wp^T + bp  (fp32 out)
    gemm_nt<M_OUT><<<dim3(6, 64, 1), 256, 0, stream>>>(Ob, 768, 0, Wpb, 768, 0, out, 768, 0, bp, nullptr, 1.0f, 768);
}

// Round 3
// 166.058 us; speedup vs baseline: 1.3095x; 1.0300x over previous
//
#include <hip/hip_runtime.h>
#include <hip/hip_bf16.h>
#include <math.h>

typedef __bf16 bf16x8 __attribute__((ext_vector_type(8)));
typedef float  f32x4  __attribute__((ext_vector_type(4)));
typedef float  f32x4v __attribute__((ext_vector_type(4)));
typedef unsigned short ushort_t;
typedef ushort_t u16x4 __attribute__((ext_vector_type(4)));
typedef ushort_t u16x8 __attribute__((ext_vector_type(8)));

__device__ __forceinline__ ushort_t f2bf(float f) {
    unsigned u = __builtin_bit_cast(unsigned, f);
    u += 0x7FFFu + ((u >> 16) & 1u);
    return (ushort_t)(u >> 16);
}
__device__ __forceinline__ float bf2f(ushort_t b) {
    return __builtin_bit_cast(float, (unsigned)b << 16);
}

// XCD-aware bijective remap (m157/m204). Requires total grid % 8 == 0.
__device__ __forceinline__ void xcd_remap(int& bx, int& by, int& bz) {
    const int gx = gridDim.x, gy = gridDim.y;
    const int nwg = gx * gy * gridDim.z;
    const int lin = (blockIdx.z * gy + blockIdx.y) * gx + blockIdx.x;
    const int chunk = nwg >> 3;
    int nid = (lin & 7) * chunk + (lin >> 3);
    bx = nid % gx; nid /= gx;
    by = nid % gy; bz = nid / gy;
}

// ---------------- fp32 -> bf16 conversion (z-batched, up to 4 arrays) --------
__global__ __launch_bounds__(256) void cvt_multi(const float* __restrict__ i0, const float* __restrict__ i1,
                                                 const float* __restrict__ i2, const float* __restrict__ i3,
                                                 ushort_t* __restrict__ o0, ushort_t* __restrict__ o1,
                                                 ushort_t* __restrict__ o2, ushort_t* __restrict__ o3, int n4) {
    const int z = blockIdx.z;
    const float* in  = z == 0 ? i0 : z == 1 ? i1 : z == 2 ? i2 : i3;
    ushort_t*    out = z == 0 ? o0 : z == 1 ? o1 : z == 2 ? o2 : o3;
    int i = blockIdx.x * 256 + threadIdx.x;
    if (i >= n4) return;
    f32x4v v = ((const f32x4v*)in)[i];
    u16x4 o = { f2bf(v.x), f2bf(v.y), f2bf(v.z), f2bf(v.w) };
    ((u16x4*)out)[i] = o;
}

__global__ __launch_bounds__(256) void zero_f32(float* __restrict__ p, int n) {
    int i = blockIdx.x * 256 + threadIdx.x;
    if (i < n) p[i] = 0.f;
}

// ---------------- NT GEMM: C = A(MxK) * B(NxK)^T ----------------
#define M_SEXP 0   // P~ = exp(scale*acc) bf16 out, batched, + rowsum atomics
#define M_PVN  1   // bf16 out * (1/rowsum[row]), batched
#define M_OUT  2   // fp32 out + bias

#define BM 128
#define BN 128
#define BK 32

#define GEMM_CORE(Ab_, lda_, Bb_, ldb_, Kdim_)                                              \
    __shared__ __align__(16) ushort_t lds[2][2][BM * BK];                                   \
    const int tid  = threadIdx.x;                                                           \
    const int lane = tid & 63;                                                              \
    const int wave = tid >> 6;                                                              \
    const int wr = wave >> 1, wc = wave & 1;                                                \
    f32x4 acc[4][4];                                                                        \
    _Pragma("unroll") for (int i = 0; i < 4; ++i)                                           \
        _Pragma("unroll") for (int j = 0; j < 4; ++j)                                       \
            acc[i][j] = (f32x4){0.f, 0.f, 0.f, 0.f};                                        \
    auto stage = [&](int buf, int kt) {                                                     \
        const int k0 = kt * BK;                                                             \
        _Pragma("unroll") for (int rnd = 0; rnd < 2; ++rnd) {                               \
            const int c    = tid + rnd * 256;                                               \
            const int row  = c >> 2;                                                        \
            const int slot = (c & 3) ^ (row & 3);                                           \
            const ushort_t* ga = (Ab_) + (tM + row) * (long long)(lda_) + k0 + slot * 8;    \
            const ushort_t* gb = (Bb_) + (tN + row) * (long long)(ldb_) + k0 + slot * 8;    \
            ushort_t* la = &lds[buf][0][(rnd * 256 + wave * 64) * 8];                       \
            ushort_t* lb = &lds[buf][1][(rnd * 256 + wave * 64) * 8];                       \
            __builtin_amdgcn_global_load_lds((const __attribute__((address_space(1))) void*)ga, \
                                             (__attribute__((address_space(3))) void*)la, 16, 0, 0); \
            __builtin_amdgcn_global_load_lds((const __attribute__((address_space(1))) void*)gb, \
                                             (__attribute__((address_space(3))) void*)lb, 16, 0, 0); \
        }                                                                                   \
    };                                                                                      \
    auto compute = [&](int buf) {                                                           \
        const int kb  = lane >> 4;                                                          \
        const int r16 = lane & 15;                                                          \
        bf16x8 af[4], bfr[4];                                                               \
        _Pragma("unroll") for (int mi = 0; mi < 4; ++mi) {                                  \
            const int row = wr * 64 + mi * 16 + r16;                                        \
            const int off = row * 64 + ((kb ^ (row & 3)) << 4);                             \
            af[mi] = *(const bf16x8*)((const char*)lds[buf][0] + off);                      \
        }                                                                                   \
        _Pragma("unroll") for (int ni = 0; ni < 4; ++ni) {                                  \
            const int row = wc * 64 + ni * 16 + r16;                                        \
            const int off = row * 64 + ((kb ^ (row & 3)) << 4);                             \
            bfr[ni] = *(const bf16x8*)((const char*)lds[buf][1] + off);                     \
        }                                                                                   \
        _Pragma("unroll") for (int mi = 0; mi < 4; ++mi)                                    \
            _Pragma("unroll") for (int ni = 0; ni < 4; ++ni)                                \
                acc[mi][ni] = __builtin_amdgcn_mfma_f32_16x16x32_bf16(af[mi], bfr[ni], acc[mi][ni], 0, 0, 0); \
    };                                                                                      \
    const int NT = (Kdim_) / BK;                                                            \
    stage(0, 0);                                                                            \
    __syncthreads();                                                                        \
    int cur = 0;                                                                            \
    for (int kt = 0; kt + 1 < NT; ++kt) {                                                   \
        stage(cur ^ 1, kt + 1);                                                             \
        compute(cur);                                                                       \
        __syncthreads();                                                                    \
        cur ^= 1;                                                                           \
    }                                                                                       \
    compute(cur);                                                                           \
    const int rquad = (lane >> 4) * 4;                                                      \
    const int cl    = lane & 15;

template<int MODE>
__global__ __launch_bounds__(256, 3)
void gemm_nt(const ushort_t* __restrict__ A, int lda, long long aBatch,
             const ushort_t* __restrict__ B, int ldb, long long bBatch,
             void* __restrict__ Cv, int ldc, long long cBatch,
             const float* __restrict__ bias, float* __restrict__ rowsum,
             float scale, int K)
{
    int bx, by, bz;
    xcd_remap(bx, by, bz);
    const long long tM = (long long)by * BM;
    const long long tN = (long long)bx * BN;
    const int z = bz;
    const ushort_t* Ab = A + (long long)z * aBatch;
    const ushort_t* Bb = B + (long long)z * bBatch;

    GEMM_CORE(Ab, lda, Bb, ldb, K)

#pragma unroll
    for (int mi = 0; mi < 4; ++mi) {
        const long long r = tM + wr * 64 + mi * 16 + rquad;   // rows r..r+3
        if constexpr (MODE == M_SEXP) {
            ushort_t* out = (ushort_t*)Cv + (long long)z * cBatch;
            float rs[4] = {0.f, 0.f, 0.f, 0.f};
#pragma unroll
            for (int ni = 0; ni < 4; ++ni) {
                f32x4 v = acc[mi][ni];
                const long long c = tN + wc * 64 + ni * 16 + cl;
#pragma unroll
                for (int j = 0; j < 4; ++j) {
                    float p = __expf(v[j] * scale);
                    ushort_t pb = f2bf(p);
                    out[(r + j) * ldc + c] = pb;
                    rs[j] += bf2f(pb);     // sum exactly what PV will read
                }
            }
#pragma unroll
            for (int j = 0; j < 4; ++j) {
                float s = rs[j];
                s += __shfl_xor(s, 1, 64);
                s += __shfl_xor(s, 2, 64);
                s += __shfl_xor(s, 4, 64);
                s += __shfl_xor(s, 8, 64);
                if (cl == 0) atomicAdd(&rowsum[(long long)z * 2048 + r + j], s);
            }
        } else if constexpr (MODE == M_PVN) {
            ushort_t* out = (ushort_t*)Cv + (long long)z * cBatch;
            float inv[4];
#pragma unroll
            for (int j = 0; j < 4; ++j)
                inv[j] = 1.0f / rowsum[(long long)z * 2048 + r + j];
#pragma unroll
            for (int ni = 0; ni < 4; ++ni) {
                f32x4 v = acc[mi][ni];
                const long long c = tN + wc * 64 + ni * 16 + cl;
#pragma unroll
                for (int j = 0; j < 4; ++j)
                    out[(r + j) * ldc + c] = f2bf(v[j] * inv[j]);
            }
        } else {  // M_OUT
            float* out = (float*)Cv;
#pragma unroll
            for (int ni = 0; ni < 4; ++ni) {
                f32x4 v = acc[mi][ni];
                const long long c = tN + wc * 64 + ni * 16 + cl;
                const float bc = bias[c];
#pragma unroll
                for (int j = 0; j < 4; ++j)
                    out[(r + j) * ldc + c] = v[j] + bc;
            }
        }
    }
}

// ------------- batched QKV projection --------------------------------------
// z=0: qp = qb@Wq^T+bq   [8192x768]
// z=1: kp = kb@Wk^T+bk   [8192x768]
// z=2: vpT = Wv@vb^T + bv (per-ROW bias) -> [768][8192], i.e. Vp^T with
//      column index = global token (b*2048+n). Coalesced row-major store;
//      this replaces the old 4KB-stride scatter store of vp^T.
__global__ __launch_bounds__(256, 3)
void proj_qkv(const ushort_t* __restrict__ a0, const ushort_t* __restrict__ a1, const ushort_t* __restrict__ a2,
              const ushort_t* __restrict__ w0, const ushort_t* __restrict__ w1, const ushort_t* __restrict__ w2,
              const float* __restrict__ b0, const float* __restrict__ b1, const float* __restrict__ b2,
              ushort_t* __restrict__ dq, ushort_t* __restrict__ dk, ushort_t* __restrict__ dvT)
{
    int bx, by, bz;
    xcd_remap(bx, by, bz);
    const int z = bz;
    // z<2: M = tokens (64 tiles via by), N = features (6 tiles via bx)
    // z=2: M = features (6 tiles via bx), N = tokens (64 tiles via by)
    const long long tM = (z < 2) ? (long long)by * BM : (long long)bx * BM;
    const long long tN = (z < 2) ? (long long)bx * BN : (long long)by * BN;
    const ushort_t* Ab = z == 0 ? a0 : z == 1 ? a1 : w2;
    const ushort_t* Bb = z == 0 ? w0 : z == 1 ? w1 : a2;
    const float* bias  = z == 0 ? b0 : z == 1 ? b1 : b2;

    GEMM_CORE(Ab, 768, Bb, 768, 768)

#pragma unroll
    for (int mi = 0; mi < 4; ++mi) {
        const long long r = tM + wr * 64 + mi * 16 + rquad;
        if (z < 2) {
            ushort_t* dst = z == 0 ? dq : dk;
#pragma unroll
            for (int ni = 0; ni < 4; ++ni) {
                f32x4 v = acc[mi][ni];
                const long long c = tN + wc * 64 + ni * 16 + cl;
                const float bc = bias[c];
#pragma unroll
                for (int j = 0; j < 4; ++j)
                    dst[(r + j) * 768 + c] = f2bf(v[j] + bc);
            }
        } else {
#pragma unroll
            for (int ni = 0; ni < 4; ++ni) {
                f32x4 v = acc[mi][ni];
                const long long c = tN + wc * 64 + ni * 16 + cl;
#pragma unroll
                for (int j = 0; j < 4; ++j)
                    dvT[(r + j) * 8192 + c] = f2bf(v[j] + bias[r + j]);
            }
        }
    }
}

// ---------------- launch ----------------
extern "C" void kernel_launch(void* const* d_in, const int* in_sizes, int n_in,
                              void* d_out, int out_size, void* d_ws, size_t ws_size,
                              hipStream_t stream) {
    (void)in_sizes; (void)n_in; (void)out_size; (void)ws_size;
    const float* q  = (const float*)d_in[0];
    const float* k  = (const float*)d_in[1];
    const float* v  = (const float*)d_in[2];
    const float* Wq = (const float*)d_in[3];
    const float* bq = (const float*)d_in[4];
    const float* Wk = (const float*)d_in[5];
    const float* bk = (const float*)d_in[6];
    const float* Wv = (const float*)d_in[7];
    const float* bv = (const float*)d_in[8];
    const float* Wp = (const float*)d_in[9];
    const float* bp = (const float*)d_in[10];
    float* out = (float*)d_out;

    char* ws = (char*)d_ws;
    // phase 1: bf16 copies of q,k,v at ws+0 (dead after projections)
    ushort_t* qb  = (ushort_t*)(ws);
    ushort_t* kb  = (ushort_t*)(ws + 12582912LL);
    ushort_t* vb  = (ushort_t*)(ws + 25165824LL);
    // phase 2 overlay: P~ bf16 [4][2048][2048] + rowsum[8192]
    ushort_t* P   = (ushort_t*)(ws);
    float* rowsum = (float*)(ws + 33554432LL);
    ushort_t* Wqb = (ushort_t*)(ws + 67108864LL);
    ushort_t* Wkb = (ushort_t*)(ws + 68288512LL);
    ushort_t* Wvb = (ushort_t*)(ws + 69468160LL);
    ushort_t* Wpb = (ushort_t*)(ws + 70647808LL);
    ushort_t* qp  = (ushort_t*)(ws + 71827456LL);    // [8192][768] bf16
    ushort_t* kp  = (ushort_t*)(ws + 84410368LL);    // [8192][768] bf16
    ushort_t* vpT = (ushort_t*)(ws + 96993280LL);    // [768][8192] bf16 (Vp^T, col=global token)
    ushort_t* Ob  = qp;                              // O overlays dead qp

    const float scale = 1.0f / sqrtf(768.0f);

    cvt_multi<<<dim3(6144, 1, 3), 256, 0, stream>>>(q, k, v, nullptr, qb, kb, vb, nullptr, 1572864);
    cvt_multi<<<dim3(576, 1, 4), 256, 0, stream>>>(Wq, Wk, Wv, Wp, Wqb, Wkb, Wvb, Wpb, 147456);

    // projections (batched): qp, kp, vpT
    proj_qkv<<<dim3(6, 64, 3), 256, 0, stream>>>(qb, kb, vb, Wqb, Wkb, Wvb, bq, bk, bv, qp, kp, vpT);

    // rowsum = 0 (overlays dead vb region)
    zero_f32<<<32, 256, 0, stream>>>(rowsum, 8192);

    // P~[b] = exp(scale * qp[b] @ kp[b]^T) bf16, rowsum += partial sums
    gemm_nt<M_SEXP><<<dim3(16, 16, 4), 256, 0, stream>>>(qp, 768, 1572864, kp, 768, 1572864,
                                                         P, 2048, 4194304, nullptr, rowsum, scale, 768);

    // O[b] = (P~[b] @ Vp^T[b]) * 1/rowsum ; B = vpT [768][8192], batch offset 2048 cols
    gemm_nt<M_PVN><<<dim3(6, 16, 4), 256, 0, stream>>>(P, 2048, 4194304, vpT, 8192, 2048,
                                                       Ob, 768, 1572864, nullptr, rowsum, 1.0f, 2048);

    // out = O @ Wp^T + bp  (fp32 out)
    gemm_nt<M_OUT><<<dim3(6, 64, 1), 256, 0, stream>>>(Ob, 768, 0, Wpb, 768, 0, out, 768, 0, bp, nullptr, 1.0f, 768);
}